// Round 13
// baseline (146.764 us; speedup 1.0000x reference)
//
#include <hip/hip_runtime.h>

// Morphological max-plus dilation, 'same' padding, K=5.
// out[b,o,y,x] = max_{c,i,j} f[b,c,y+i-2,x+j-2] + h[o,c,i,j]
// f(8,32,96,96) fp32, h(32,32,5,5) fp32, out(8,32,96,96) fp32.
//
// R13 = R12 with the add moved to the FMA pipe: v_pk_fma_f16(fv,1.0,hv)
// (exact: x*1.0 single-rounded == add). R12 established: 29.5M pk wave-instrs
// at measured ~4.15 cyc each (busy 49.8us), memory & occupancy irrelevant.
// m07 measured v_fma_f32 at ~2 cyc -> if the FMA pipe issues 2x faster than
// add/max, busy drops to ~37us. Also: c-pair halves reduced to scalar fp16
// BEFORE the LDS combine (comb 18.4 -> 9.2 KB).
//  - C-PAIR packed f (2 c-planes per dword) in d_ws, NEG halo
//  - R8 grid: 1536 blocks x 384 thr, 4 c-split groups (4 c-pairs each)

#define B_ 8
#define C_ 32
#define O_ 32
#define H_ 96
#define W_ 96
#define K_ 5
#define KK_ (K_ * K_)      // 25
#define NCP_ (C_ / 2)      // 16 c-pairs

#define TX_ 24             // threads along x; 24*4 = 96 = W
#define RT_ 4              // row-threads per group (4 output rows per block)
#define CS_ 4              // in-block c-split groups
#define TY_ (RT_ * CS_)    // 16
#define NT_ (TX_ * TY_)    // 384 threads = 6 waves
#define XR_ 4              // x outputs per thread
#define OB_ 4              // o-channels per block (one per acc row)
#define CPG_ (NCP_ / CS_)  // 4 c-pairs per group

// padded f: [b][cp][PH][PW] dwords; row = y+2 (0..99), col = x+2 (pad to 104)
#define PH_ 100
#define PW_ 104
#define PLSZ_ (PH_ * PW_)
#define FPAD_BYTES ((size_t)B_ * NCP_ * PLSZ_ * 4)   // ~5.3 MB

#define NEGF (-30000.0f)

typedef _Float16 h2 __attribute__((ext_vector_type(2)));

static __device__ __forceinline__ h2 h2b(unsigned u) {
    return __builtin_bit_cast(h2, u);
}
static __device__ __forceinline__ unsigned bh2(h2 v) {
    return __builtin_bit_cast(unsigned, v);
}

// acc = pk_max(acc, pk_fma(fv, 1.0, hv)) -- add on the FMA pipe.
static __device__ __forceinline__ void pk_fmamax(h2& acc, h2 fv, h2 hv, h2 one) {
    h2 t;
    asm("v_pk_fma_f16 %0, %1, %2, %3" : "=v"(t) : "v"(fv), "v"(one), "v"(hv));
    asm("v_pk_max_f16 %0, %1, %2" : "=v"(acc) : "v"(acc), "v"(t));
}

// ---------------- pre-pad: two c-planes packed per dword, NEG halo -----------
__global__ __launch_bounds__(256)
void prepad_kernel(const float* __restrict__ f, unsigned* __restrict__ fpad) {
    const int idx = blockIdx.x * 256 + threadIdx.x;
    const int cp = blockIdx.y;            // 0..15
    const int b  = blockIdx.z;
    if (idx >= PLSZ_) return;
    const int row = idx / PW_;
    const int col = idx - row * PW_;
    const int y = row - 2;
    const int x = col - 2;
    float v0 = NEGF, v1 = NEGF;
    if ((unsigned)y < H_ && (unsigned)x < W_) {
        v0 = f[((size_t)(b * C_ + 2 * cp)     * H_ + y) * W_ + x];
        v1 = f[((size_t)(b * C_ + 2 * cp + 1) * H_ + y) * W_ + x];
    }
    h2 d; d.x = (_Float16)v0; d.y = (_Float16)v1;
    fpad[(size_t)(b * NCP_ + cp) * PLSZ_ + idx] = bh2(d);
}

// ---------------- main kernel ------------------------------------------------
template <bool PADDED>
__global__ __launch_bounds__(NT_)
void dilate_main(const unsigned* __restrict__ fpad,
                 const float* __restrict__ f,
                 const float* __restrict__ h, float* __restrict__ out) {
    const int tx  = threadIdx.x;           // 0..23
    const int ty  = threadIdx.y;           // 0..15
    const int tid = ty * TX_ + tx;         // 0..383
    const int ry  = ty & (RT_ - 1);        // row-thread 0..3
    const int g   = ty >> 2;               // c-split group 0..3

    const int ytile = blockIdx.x;          // 0..23
    const int og    = blockIdx.y;          // 0..7
    const int b     = blockIdx.z;          // 0..7
    const int y0 = ytile * RT_;            // 4 rows per block
    const int o0 = og * OB_;
    const int x0 = XR_ * tx;               // 0..92
    const int yb = y0 + ry;                // this thread's output row

    // hs2[cp][ij*4+o] = h2(h[o0+o][2cp][ij], h[o0+o][2cp+1][ij]); stride 104
    __shared__ unsigned hs2[NCP_][104];                            // 6656 B
    __shared__ unsigned short comb[CS_ - 1][OB_ * XR_][RT_ * TX_]; // 9216 B

    for (int idx = tid; idx < NCP_ * KK_ * OB_; idx += NT_) {
        int cp = idx / (KK_ * OB_);
        int rr = idx - cp * (KK_ * OB_);
        int ij = rr / OB_;
        int o  = rr - ij * OB_;
        float a0 = h[((size_t)(o0 + o) * C_ + 2 * cp)     * KK_ + ij];
        float a1 = h[((size_t)(o0 + o) * C_ + 2 * cp + 1) * KK_ + ij];
        h2 p; p.x = (_Float16)a0; p.y = (_Float16)a1;
        hs2[cp][ij * OB_ + o] = bh2(p);
    }
    __syncthreads();

    h2 acc[OB_][XR_];   // per-half running max over its c-subset
    h2 one;
    {
        h2 neg; neg.x = (_Float16)NEGF; neg.y = (_Float16)NEGF;
        one.x = (_Float16)1.0f; one.y = (_Float16)1.0f;
#pragma unroll
        for (int o = 0; o < OB_; ++o)
#pragma unroll
            for (int xx = 0; xx < XR_; ++xx) acc[o][xx] = neg;
    }

    const int cp0 = g * CPG_;
    for (int cpi = 0; cpi < CPG_; ++cpi) {
        const int cp = cp0 + cpi;

        // ---- window: 5 rows x 8 dwords (each dword = 2 c's of one pixel) ----
        h2 win[K_][8];
        if (PADDED) {
            const unsigned* p =
                fpad + (size_t)(b * NCP_ + cp) * PLSZ_ + yb * PW_ + x0;
#pragma unroll
            for (int i = 0; i < K_; ++i) {
                const uint4* q = (const uint4*)(p + i * PW_);
                uint4 w0 = q[0];
                uint4 w1 = q[1];
                win[i][0] = h2b(w0.x); win[i][1] = h2b(w0.y);
                win[i][2] = h2b(w0.z); win[i][3] = h2b(w0.w);
                win[i][4] = h2b(w1.x); win[i][5] = h2b(w1.y);
                win[i][6] = h2b(w1.z); win[i][7] = h2b(w1.w);
            }
        } else {
            const float* fc0 = f + (size_t)(b * C_ + 2 * cp) * (H_ * W_);
            const float* fc1 = f + (size_t)(b * C_ + 2 * cp + 1) * (H_ * W_);
#pragma unroll
            for (int i = 0; i < K_; ++i) {
#pragma unroll
                for (int q = 0; q < 8; ++q) {
                    int yy = yb + i - 2;
                    int xc = x0 - 2 + q;
                    bool ok = ((unsigned)yy < H_) && ((unsigned)xc < W_);
                    float v0 = ok ? fc0[(size_t)yy * W_ + xc] : NEGF;
                    float v1 = ok ? fc1[(size_t)yy * W_ + xc] : NEGF;
                    h2 d; d.x = (_Float16)v0; d.y = (_Float16)v1;
                    win[i][q] = d;
                }
            }
        }

        // ---- math: per (ij): one uint4 h read, 16 pk_fma + 16 pk_max --------
#pragma unroll
        for (int i = 0; i < K_; ++i) {
#pragma unroll
            for (int j = 0; j < K_; ++j) {
                uint4 hq = *(const uint4*)&hs2[cp][(i * K_ + j) * OB_];
                h2 h0 = h2b(hq.x), h1 = h2b(hq.y);
                h2 h02 = h2b(hq.z), h3 = h2b(hq.w);
#pragma unroll
                for (int xx = 0; xx < XR_; ++xx) {
                    h2 fv = win[i][xx + j];
                    pk_fmamax(acc[0][xx], fv, h0, one);
                    pk_fmamax(acc[1][xx], fv, h1, one);
                    pk_fmamax(acc[2][xx], fv, h02, one);
                    pk_fmamax(acc[3][xx], fv, h3, one);
                }
            }
        }
    }

    // ---- reduce c-pair halves to scalar fp16 (all groups) --------------------
    unsigned short red[OB_][XR_];
#pragma unroll
    for (int o = 0; o < OB_; ++o)
#pragma unroll
        for (int xx = 0; xx < XR_; ++xx) {
            _Float16 a = acc[o][xx].x;
            _Float16 b2 = acc[o][xx].y;
            _Float16 m = (a > b2) ? a : b2;
            red[o][xx] = __builtin_bit_cast(unsigned short, m);
        }

    // ---- combine the four c-groups via LDS (lane-contiguous) ----------------
    const int t96 = ry * TX_ + tx;   // 0..95 within group
    if (g > 0) {
#pragma unroll
        for (int o = 0; o < OB_; ++o)
#pragma unroll
            for (int xx = 0; xx < XR_; ++xx)
                comb[g - 1][o * XR_ + xx][t96] = red[o][xx];
    }
    __syncthreads();
    if (g == 0) {
        const int y = yb;
#pragma unroll
        for (int o = 0; o < OB_; ++o) {
            float r[XR_];
#pragma unroll
            for (int xx = 0; xx < XR_; ++xx) {
                const int row = o * XR_ + xx;
                _Float16 m = __builtin_bit_cast(_Float16, red[o][xx]);
                _Float16 v0 = __builtin_bit_cast(_Float16, comb[0][row][t96]);
                _Float16 v1 = __builtin_bit_cast(_Float16, comb[1][row][t96]);
                _Float16 v2 = __builtin_bit_cast(_Float16, comb[2][row][t96]);
                m = (v0 > m) ? v0 : m;
                m = (v1 > m) ? v1 : m;
                m = (v2 > m) ? v2 : m;
                r[xx] = (float)m;
            }
            float4 v = make_float4(r[0], r[1], r[2], r[3]);
            *(float4*)&out[(((size_t)b * O_ + (o0 + o)) * H_ + y) * W_ + x0] = v;
        }
    }
}

extern "C" void kernel_launch(void* const* d_in, const int* in_sizes, int n_in,
                              void* d_out, int out_size, void* d_ws, size_t ws_size,
                              hipStream_t stream) {
    const float* f = (const float*)d_in[0];
    const float* h = (const float*)d_in[1];
    float* out = (float*)d_out;

    dim3 mgrid(H_ / RT_, O_ / OB_, B_);   // (24, 8, 8) = 1536 blocks
    dim3 mblock(TX_, TY_);                // 384 threads = 6 waves

    if (ws_size >= FPAD_BYTES) {
        unsigned* fpad = (unsigned*)d_ws;
        dim3 pgrid((PLSZ_ + 255) / 256, NCP_, B_);
        hipLaunchKernelGGL(prepad_kernel, pgrid, dim3(256), 0, stream, f, fpad);
        hipLaunchKernelGGL((dilate_main<true>), mgrid, mblock, 0, stream,
                           fpad, f, h, out);
    } else {
        hipLaunchKernelGGL((dilate_main<false>), mgrid, mblock, 0, stream,
                           (const unsigned*)nullptr, f, h, out);
    }
}

// Round 15
// 139.880 us; speedup vs baseline: 1.0492x; 1.0492x over previous
//
#include <hip/hip_runtime.h>

// Morphological max-plus dilation, 'same' padding, K=5.
// out[b,o,y,x] = max_{c,i,j} f[b,c,y+i-2,x+j-2] + h[o,c,i,j]
// f(8,32,96,96) fp32, h(32,32,5,5) fp32, out(8,32,96,96) fp32.
//
// R15 = R14 with the h-block pointer made provably wave-uniform via
// __builtin_amdgcn_readfirstlane(g). R14 failed to compile because
// g = ty>>3 is threadIdx-derived: the compiler kept hp in VGPRs and
// s_load_dwordx8 got a v[] address operand. g IS wave-uniform (192-thr
// groups = 3 whole waves), so readfirstlane is legal and moves the whole
// address chain to SGPRs.
// Theory unchanged: 29.5M pk instrs x 4.15 cyc = 50us busy (measured,
// invariant); the ~40us idle matches 25 serial per-ij h-reads per cp iter.
// This kernel gives the math loop ZERO in-loop LDS/SMEM dependency: h lives
// in SGPRs (VOP3P "s" operand legal), loaded by hand-written
// s_load_dwordx8 blocks with in-asm s_waitcnt (un-sinkable).
//  - C-PAIR packed f (2 c-planes per dword) in d_ws, NEG halo
//  - 768 blocks x 384 thr (6 waves), 2 wave-aligned c-split groups

#define B_ 8
#define C_ 32
#define O_ 32
#define H_ 96
#define W_ 96
#define K_ 5
#define KK_ (K_ * K_)      // 25
#define NCP_ (C_ / 2)      // 16 c-pairs

#define TX_ 24             // threads along x; 24*4 = 96 = W
#define RT_ 8              // row-threads per group (8 output rows per block)
#define CS_ 2              // c-split groups (WAVE-ALIGNED: 192 thr = 3 waves)
#define TY_ (RT_ * CS_)    // 16
#define NT_ (TX_ * TY_)    // 384 threads = 6 waves
#define XR_ 4              // x outputs per thread
#define OB_ 4              // o-channels per block
#define CPG_ (NCP_ / CS_)  // 8 c-pairs per group

// padded f: [b][cp][PH][PW] dwords; row = y+2 (0..99), col = x+2 (pad to 104)
#define PH_ 100
#define PW_ 104
#define PLSZ_ (PH_ * PW_)
#define FPAD_BYTES ((size_t)B_ * NCP_ * PLSZ_ * 4)   // ~5.3 MB

// packed h in d_ws after fpad: [og][cp] blocks of 128 dwords (100 used):
// dword[ij*4+o] = h2(h[og*4+o][2cp][ij], h[og*4+o][2cp+1][ij])
#define HBLK_ 128
#define HPACK_DW (8 * NCP_ * HBLK_)                  // 16384 dw = 64 KB

#define NEGF (-30000.0f)

typedef _Float16 h2 __attribute__((ext_vector_type(2)));
typedef int sv8 __attribute__((ext_vector_type(8)));
typedef int sv4 __attribute__((ext_vector_type(4)));

static __device__ __forceinline__ h2 h2b(unsigned u) {
    return __builtin_bit_cast(h2, u);
}
static __device__ __forceinline__ unsigned bh2(h2 v) {
    return __builtin_bit_cast(unsigned, v);
}

// acc = pk_max(acc, fv + h) with h coming from an SGPR.
static __device__ __forceinline__ void pk_addmax_s(h2& acc, h2 fv, int hs) {
    h2 t;
    asm("v_pk_add_f16 %0, %1, %2" : "=v"(t) : "v"(fv), "s"(hs));
    asm("v_pk_max_f16 %0, %1, %2" : "=v"(acc) : "v"(acc), "v"(t));
}

static __device__ __forceinline__ int hgetA(sv8 a0, sv8 a1, sv8 a2, sv8 a3,
                                            sv8 a4, sv8 a5, int n) {
    if (n < 8)  return a0[n];
    if (n < 16) return a1[n - 8];
    if (n < 24) return a2[n - 16];
    if (n < 32) return a3[n - 24];
    if (n < 40) return a4[n - 32];
    return a5[n - 40];
}
static __device__ __forceinline__ int hgetB(sv8 a0, sv8 a1, sv8 a2, sv8 a3,
                                            sv8 a4, sv8 a5, sv4 b, int n) {
    if (n < 48) return hgetA(a0, a1, a2, a3, a4, a5, n);
    return b[n - 48];
}

// ---------------- pre-pad: two c-planes packed per dword, NEG halo -----------
__global__ __launch_bounds__(256)
void prepad_kernel(const float* __restrict__ f, unsigned* __restrict__ fpad) {
    const int idx = blockIdx.x * 256 + threadIdx.x;
    const int cp = blockIdx.y;            // 0..15
    const int b  = blockIdx.z;
    if (idx >= PLSZ_) return;
    const int row = idx / PW_;
    const int col = idx - row * PW_;
    const int y = row - 2;
    const int x = col - 2;
    float v0 = NEGF, v1 = NEGF;
    if ((unsigned)y < H_ && (unsigned)x < W_) {
        v0 = f[((size_t)(b * C_ + 2 * cp)     * H_ + y) * W_ + x];
        v1 = f[((size_t)(b * C_ + 2 * cp + 1) * H_ + y) * W_ + x];
    }
    h2 d; d.x = (_Float16)v0; d.y = (_Float16)v1;
    fpad[(size_t)(b * NCP_ + cp) * PLSZ_ + idx] = bh2(d);
}

// ---------------- pack h ------------------------------------------------------
__global__ __launch_bounds__(256)
void hpack_kernel(const float* __restrict__ h, unsigned* __restrict__ hpack) {
    const int idx = blockIdx.x * 256 + threadIdx.x;
    if (idx >= 8 * NCP_ * KK_ * OB_) return;
    const int og = idx / (NCP_ * KK_ * OB_);
    int r  = idx - og * (NCP_ * KK_ * OB_);
    const int cp = r / (KK_ * OB_);
    r -= cp * (KK_ * OB_);
    const int ij = r / OB_;
    const int o  = r - ij * OB_;
    float a0 = h[((size_t)(og * OB_ + o) * C_ + 2 * cp)     * KK_ + ij];
    float a1 = h[((size_t)(og * OB_ + o) * C_ + 2 * cp + 1) * KK_ + ij];
    h2 p; p.x = (_Float16)a0; p.y = (_Float16)a1;
    hpack[(size_t)(og * NCP_ + cp) * HBLK_ + ij * OB_ + o] = bh2(p);
}

// ---------------- main kernel ------------------------------------------------
__global__ __launch_bounds__(NT_)
void dilate_main(const unsigned* __restrict__ fpad,
                 const unsigned* __restrict__ hpack,
                 float* __restrict__ out) {
    const int tx  = threadIdx.x;           // 0..23
    const int ty  = threadIdx.y;           // 0..15
    const int ry  = ty & (RT_ - 1);        // 0..7
    const int g   = ty >> 3;               // 0..1, wave-uniform (192-thr groups)
    // Provably-uniform copy for the scalar h path (compiler can't prove
    // ty>>3 uniform on its own; readfirstlane forces SGPR).
    const int gu  = __builtin_amdgcn_readfirstlane(g);

    const int ytile = blockIdx.x;          // 0..11
    const int og    = blockIdx.y;          // 0..7
    const int b     = blockIdx.z;          // 0..7
    const int y0 = ytile * RT_;            // 8 rows per block
    const int o0 = og * OB_;
    const int x0 = XR_ * tx;               // 0..92
    const int yb = y0 + ry;                // this thread's output row

    __shared__ unsigned short comb[OB_ * XR_][RT_ * TX_];   // 16 x 192 x 2 = 6144 B

    h2 acc[OB_][XR_];   // per-half running max over its c-subset
    {
        h2 neg; neg.x = (_Float16)NEGF; neg.y = (_Float16)NEGF;
#pragma unroll
        for (int o = 0; o < OB_; ++o)
#pragma unroll
            for (int xx = 0; xx < XR_; ++xx) acc[o][xx] = neg;
    }

    const int cp0v = g * CPG_;    // vector copy for window addressing
    const int cp0s = gu * CPG_;   // scalar copy for h addressing
    for (int cpi = 0; cpi < CPG_; ++cpi) {
        // ---- window loads first (vmcnt latency overlaps the h s_loads) ------
        h2 win[K_][8];
        {
            const unsigned* p = fpad +
                (size_t)(b * NCP_ + cp0v + cpi) * PLSZ_ + yb * PW_ + x0;
#pragma unroll
            for (int i = 0; i < K_; ++i) {
                const uint4* q = (const uint4*)(p + i * PW_);
                uint4 w0 = q[0];
                uint4 w1 = q[1];
                win[i][0] = h2b(w0.x); win[i][1] = h2b(w0.y);
                win[i][2] = h2b(w0.z); win[i][3] = h2b(w0.w);
                win[i][4] = h2b(w1.x); win[i][5] = h2b(w1.y);
                win[i][6] = h2b(w1.z); win[i][7] = h2b(w1.w);
            }
        }

        const unsigned* hp =
            hpack + (size_t)(og * NCP_ + cp0s + cpi) * HBLK_;

        // ---- phase A: ij 0..11 (dwords 0..47) into SGPRs --------------------
        sv8 a0, a1, a2, a3, a4, a5;
        asm volatile(
            "s_load_dwordx8 %0, %6, 0x0\n\t"
            "s_load_dwordx8 %1, %6, 0x20\n\t"
            "s_load_dwordx8 %2, %6, 0x40\n\t"
            "s_load_dwordx8 %3, %6, 0x60\n\t"
            "s_load_dwordx8 %4, %6, 0x80\n\t"
            "s_load_dwordx8 %5, %6, 0xa0\n\t"
            "s_waitcnt lgkmcnt(0)"
            : "=s"(a0), "=s"(a1), "=s"(a2), "=s"(a3), "=s"(a4), "=s"(a5)
            : "s"(hp));

#pragma unroll
        for (int ij = 0; ij < 12; ++ij) {
            const int i = ij / K_, j = ij % K_;
            const int n = ij * 4;
            int h0 = hgetA(a0, a1, a2, a3, a4, a5, n);
            int h1 = hgetA(a0, a1, a2, a3, a4, a5, n + 1);
            int h2v = hgetA(a0, a1, a2, a3, a4, a5, n + 2);
            int h3 = hgetA(a0, a1, a2, a3, a4, a5, n + 3);
#pragma unroll
            for (int xx = 0; xx < XR_; ++xx) {
                h2 fv = win[i][xx + j];
                pk_addmax_s(acc[0][xx], fv, h0);
                pk_addmax_s(acc[1][xx], fv, h1);
                pk_addmax_s(acc[2][xx], fv, h2v);
                pk_addmax_s(acc[3][xx], fv, h3);
            }
        }

        // ---- phase B: ij 12..24 (dwords 48..99) into SGPRs ------------------
        sv8 b0, b1, b2, b3, b4, b5;
        sv4 bt;
        asm volatile(
            "s_load_dwordx8 %0, %7, 0xc0\n\t"
            "s_load_dwordx8 %1, %7, 0xe0\n\t"
            "s_load_dwordx8 %2, %7, 0x100\n\t"
            "s_load_dwordx8 %3, %7, 0x120\n\t"
            "s_load_dwordx8 %4, %7, 0x140\n\t"
            "s_load_dwordx8 %5, %7, 0x160\n\t"
            "s_load_dwordx4 %6, %7, 0x180\n\t"
            "s_waitcnt lgkmcnt(0)"
            : "=s"(b0), "=s"(b1), "=s"(b2), "=s"(b3), "=s"(b4), "=s"(b5),
              "=s"(bt)
            : "s"(hp));

#pragma unroll
        for (int ij = 12; ij < KK_; ++ij) {
            const int i = ij / K_, j = ij % K_;
            const int n = ij * 4 - 48;
            int h0 = hgetB(b0, b1, b2, b3, b4, b5, bt, n);
            int h1 = hgetB(b0, b1, b2, b3, b4, b5, bt, n + 1);
            int h2v = hgetB(b0, b1, b2, b3, b4, b5, bt, n + 2);
            int h3 = hgetB(b0, b1, b2, b3, b4, b5, bt, n + 3);
#pragma unroll
            for (int xx = 0; xx < XR_; ++xx) {
                h2 fv = win[i][xx + j];
                pk_addmax_s(acc[0][xx], fv, h0);
                pk_addmax_s(acc[1][xx], fv, h1);
                pk_addmax_s(acc[2][xx], fv, h2v);
                pk_addmax_s(acc[3][xx], fv, h3);
            }
        }
    }

    // ---- reduce c-pair halves to scalar fp16 ---------------------------------
    unsigned short red[OB_][XR_];
#pragma unroll
    for (int o = 0; o < OB_; ++o)
#pragma unroll
        for (int xx = 0; xx < XR_; ++xx) {
            _Float16 a = acc[o][xx].x;
            _Float16 b2 = acc[o][xx].y;
            _Float16 m = (a > b2) ? a : b2;
            red[o][xx] = __builtin_bit_cast(unsigned short, m);
        }

    // ---- combine the two c-groups via LDS ------------------------------------
    const int t192 = ry * TX_ + tx;   // 0..191 within group
    if (g == 1) {
#pragma unroll
        for (int o = 0; o < OB_; ++o)
#pragma unroll
            for (int xx = 0; xx < XR_; ++xx)
                comb[o * XR_ + xx][t192] = red[o][xx];
    }
    __syncthreads();
    if (g == 0) {
        const int y = yb;
#pragma unroll
        for (int o = 0; o < OB_; ++o) {
            float r[XR_];
#pragma unroll
            for (int xx = 0; xx < XR_; ++xx) {
                _Float16 m  = __builtin_bit_cast(_Float16, red[o][xx]);
                _Float16 v0 = __builtin_bit_cast(_Float16,
                                                 comb[o * XR_ + xx][t192]);
                m = (v0 > m) ? v0 : m;
                r[xx] = (float)m;
            }
            float4 v = make_float4(r[0], r[1], r[2], r[3]);
            *(float4*)&out[(((size_t)b * O_ + (o0 + o)) * H_ + y) * W_ + x0] = v;
        }
    }
}

// ---------------- fallback (no workspace): correctness-only ------------------
__global__ __launch_bounds__(256)
void dilate_naive(const float* __restrict__ f, const float* __restrict__ h,
                  float* __restrict__ out) {
    const int idx = blockIdx.x * 256 + threadIdx.x;
    if (idx >= B_ * O_ * H_ * W_) return;
    const int x = idx % W_;
    const int y = (idx / W_) % H_;
    const int o = (idx / (W_ * H_)) % O_;
    const int b = idx / (W_ * H_ * O_);
    float m = -3.0e38f;
    for (int c = 0; c < C_; ++c)
        for (int i = 0; i < K_; ++i)
            for (int j = 0; j < K_; ++j) {
                int yy = y + i - 2, xc = x + j - 2;
                if ((unsigned)yy < H_ && (unsigned)xc < W_) {
                    float v = f[((size_t)(b * C_ + c) * H_ + yy) * W_ + xc] +
                              h[((size_t)o * C_ + c) * KK_ + i * K_ + j];
                    m = fmaxf(m, v);
                }
            }
    out[idx] = m;
}

extern "C" void kernel_launch(void* const* d_in, const int* in_sizes, int n_in,
                              void* d_out, int out_size, void* d_ws, size_t ws_size,
                              hipStream_t stream) {
    const float* f = (const float*)d_in[0];
    const float* h = (const float*)d_in[1];
    float* out = (float*)d_out;

    const size_t need = FPAD_BYTES + (size_t)HPACK_DW * 4;
    if (ws_size >= need) {
        unsigned* fpad  = (unsigned*)d_ws;
        unsigned* hpack = (unsigned*)((char*)d_ws + FPAD_BYTES);
        dim3 pgrid((PLSZ_ + 255) / 256, NCP_, B_);
        hipLaunchKernelGGL(prepad_kernel, pgrid, dim3(256), 0, stream, f, fpad);
        hipLaunchKernelGGL(hpack_kernel,
                           dim3((8 * NCP_ * KK_ * OB_ + 255) / 256), dim3(256),
                           0, stream, h, hpack);
        dim3 mgrid(H_ / RT_, O_ / OB_, B_);   // (12, 8, 8) = 768 blocks
        dim3 mblock(TX_, TY_);                // 384 threads = 6 waves
        hipLaunchKernelGGL(dilate_main, mgrid, mblock, 0, stream,
                           fpad, hpack, out);
    } else {
        hipLaunchKernelGGL(dilate_naive,
                           dim3((B_ * O_ * H_ * W_ + 255) / 256), dim3(256),
                           0, stream, f, h, out);
    }
}